// Round 14
// baseline (457.316 us; speedup 1.0000x reference)
//
#include <hip/hip_runtime.h>
#include <math.h>
#include <stdint.h>

#define N_NODES 50000
#define FEAT    256
#define EDGES   200000
#define HEADS   4
#define CH      128
#define HID     512   // HEADS*CH
#define NGRAPH  256
#define NCLS    10

typedef unsigned short ushort_t;
typedef unsigned int uint_t;
typedef __attribute__((ext_vector_type(8))) short bf16x8;
typedef __attribute__((ext_vector_type(4))) float f32x4;
typedef __attribute__((ext_vector_type(2))) float f32x2;

__device__ __forceinline__ ushort_t f2bf(float f) {  // round-to-nearest-even
  uint_t u = __float_as_uint(f);
  u += 0x7FFF + ((u >> 16) & 1);
  return (ushort_t)(u >> 16);
}
__device__ __forceinline__ float bf2f(ushort_t h) {
  return __uint_as_float(((uint_t)h) << 16);
}
// VALU strength reduction (round-11 verified: total -44 us): ELU via __expf,
// softmax denom via v_rcp_f32.
__device__ __forceinline__ float elu1(float x) {
  return x > 0.f ? x : __expf(x) - 1.f;
}
__device__ __forceinline__ float fastrcp(float x) {
  return __builtin_amdgcn_rcpf(x);
}
__device__ __forceinline__ void unpack8(uint4 w, float* f) {
  f[0] = bf2f((ushort_t)w.x); f[1] = bf2f((ushort_t)(w.x >> 16));
  f[2] = bf2f((ushort_t)w.y); f[3] = bf2f((ushort_t)(w.y >> 16));
  f[4] = bf2f((ushort_t)w.z); f[5] = bf2f((ushort_t)(w.z >> 16));
  f[6] = bf2f((ushort_t)w.w); f[7] = bf2f((ushort_t)(w.w >> 16));
}
// 8 x fp8(e4m3) -> 8 x f32 via v_cvt_pk_f32_fp8 (4 insts)
__device__ __forceinline__ void unpack8_fp8(uint2 w, float* f) {
  f32x2 a = __builtin_amdgcn_cvt_pk_f32_fp8((int)w.x, false);
  f32x2 b = __builtin_amdgcn_cvt_pk_f32_fp8((int)w.x, true);
  f32x2 c = __builtin_amdgcn_cvt_pk_f32_fp8((int)w.y, false);
  f32x2 d = __builtin_amdgcn_cvt_pk_f32_fp8((int)w.y, true);
  f[0] = a[0]; f[1] = a[1]; f[2] = b[0]; f[3] = b[1];
  f[4] = c[0]; f[5] = c[1]; f[6] = d[0]; f[7] = d[1];
}
__device__ __forceinline__ uint_t pack4_fp8(float f0, float f1, float f2, float f3) {
  int v = __builtin_amdgcn_cvt_pk_fp8_f32(f0, f1, 0, false);
  v = __builtin_amdgcn_cvt_pk_fp8_f32(f2, f3, v, true);
  return (uint_t)v;
}

// ---------------------------------------------------------------------------
// Layout (unchanged): unified 2304-B BIG rows for BOTH layers.
//  L1: q_H @H*256, kv_H @1024+H*256 (k @c*16, v @c*16+8), H=0..3;
//      skip s_H routed by the GEMM epilogue DIRECTLY into H1b @H*256.
//  L2: q_H @H*256, kv_H @1024+H*256, skip @2048.
// ---------------------------------------------------------------------------

// ---------------------------------------------------------------------------
// GEMM (round-8 verified loop: L2 111 us, MfmaUtil 34, Occ 29.4, bank-conf 0):
// 128x128 tile, BK=32, 4 waves (2x2, per-wave 64x64), 256 threads, TRIPLE-
// buffered 48 KB LDS -> 3 blocks/CU. Single-region counted-vmcnt K-tile loop.
// vmcnt(4) at boundary keeps tile t+2's loads in flight (never 0 mid-loop).
// Chunk swizzle (r>>1)&3 on stage-source AND read side. N tiles exact:
// 2048=16x128 (mode 1), 1664=13x128 (mode 2) -> no N clamps.
// Cb2 = second output base (H1b) for mode-1 skip blocks.
// ---------------------------------------------------------------------------
__global__ __launch_bounds__(256) void gemm_bt(
    const ushort_t* __restrict__ A, const ushort_t* __restrict__ Bt,
    const float* __restrict__ bias, char* __restrict__ Cb,
    char* __restrict__ Cb2, int M, int K, int nct, int mode) {
  __shared__ __align__(16) ushort_t smem[24576];   // 3 x 16 KB K-tile buffers
  const int tid = threadIdx.x;
  const int lane = tid & 63, wave = tid >> 6;
  const int wr = wave >> 1, wc = wave & 1;         // 2M x 2N waves

  // XCD-aware decode: rowTile = grp*8 + (b%8), ct = (b/8)%nct
  int b = blockIdx.x;
  int per = nct << 3;
  int grp = b / per;
  int rem = b - grp * per;
  int rloc = rem & 7;
  int ct = rem >> 3;
  const int rowBase = (grp * 8 + rloc) * 128;
  const int colBase = ct * 128;
  if (rowBase >= M) return;

  // ---- staging: 2 A slots + 2 B slots per thread per K-tile (4 GLL) ----
  const int s0 = tid, s1 = tid + 256;              // slot = row*4 + pos
  const int rl0 = s0 >> 2, cg0 = (s0 & 3) ^ ((rl0 >> 1) & 3);
  const int rl1 = s1 >> 2, cg1 = (s1 & 3) ^ ((rl1 >> 1) & 3);
  int ra0 = rowBase + rl0; ra0 = ra0 < M ? ra0 : M - 1;   // M-tail clamp
  int ra1 = rowBase + rl1; ra1 = ra1 < M ? ra1 : M - 1;
  const ushort_t* pa0 = A + (size_t)ra0 * K + cg0 * 8;
  const ushort_t* pa1 = A + (size_t)ra1 * K + cg1 * 8;
  const ushort_t* pb0 = Bt + (size_t)(colBase + rl0) * K + cg0 * 8;
  const ushort_t* pb1 = Bt + (size_t)(colBase + rl1) * K + cg1 * 8;
  const int dA0 = s0 * 8, dA1 = s1 * 8;            // A region [0,4096) elems
  const int dB0 = 4096 + s0 * 8, dB1 = 4096 + s1 * 8;  // B region [4096,8192)

#define GLL(gp, loff)  __builtin_amdgcn_global_load_lds( \
      (const __attribute__((address_space(1))) uint_t*)(gp), \
      (__attribute__((address_space(3))) uint_t*)(smem + (loff)), 16, 0, 0)

  const int nt = K >> 5;                           // K-tiles of 32 (8 or 16)
  // ---- prologue: stage tiles 0 (buf0) and 1 (buf1) ----
  GLL(pa0, dA0);            GLL(pa1, dA1);
  GLL(pb0, dB0);            GLL(pb1, dB1);
  GLL(pa0 + 32, 8192 + dA0); GLL(pa1 + 32, 8192 + dA1);
  GLL(pb0 + 32, 8192 + dB0); GLL(pb1 + 32, 8192 + dB1);
  pa0 += 64; pa1 += 64; pb0 += 64; pb1 += 64;      // now point at tile 2

  // ---- fragment read offsets (element units) ----
  const int fr = lane & 15, c0 = lane >> 4;
  const int pswz = (c0 ^ ((fr >> 1) & 3)) * 8;     // same swizzle as stage
  const int aOff = (wr * 64 + fr) * 32 + pswz;
  const int bOff = 4096 + (wc * 64 + fr) * 32 + pswz;

  f32x4 acc[4][4] = {};
  asm volatile("s_waitcnt vmcnt(4)" ::: "memory"); // tile0 landed, tile1 in flight
  __builtin_amdgcn_s_barrier();
  __builtin_amdgcn_sched_barrier(0);

  int cur = 0, nxt = 2;
  for (int t = 0; t < nt; ++t) {
    const ushort_t* bufc = smem + cur * 8192;
    const bool pf = (t + 2) < nt;
    bf16x8 af[4], bfr[4];
    // reads ordered so the first MFMA (af[0] x bfr[0]) unblocks earliest
    af[0] = *(const bf16x8*)(bufc + aOff);
#pragma unroll
    for (int j = 0; j < 4; ++j) bfr[j] = *(const bf16x8*)(bufc + bOff + j * 512);
#pragma unroll
    for (int i = 1; i < 4; ++i) af[i] = *(const bf16x8*)(bufc + aOff + i * 512);
    // prefetch tile t+2 into buf[nxt] (drained since its lgkmcnt(0) last tile)
    if (pf) {
      int lo = nxt * 8192;
      GLL(pa0, lo + dA0); GLL(pa1, lo + dA1);
      GLL(pb0, lo + dB0); GLL(pb1, lo + dB1);
      pa0 += 32; pa1 += 32; pb0 += 32; pb1 += 32;
    }
#pragma unroll
    for (int i = 0; i < 4; ++i)
#pragma unroll
      for (int j = 0; j < 4; ++j)
        acc[i][j] = __builtin_amdgcn_mfma_f32_16x16x32_bf16(af[i], bfr[j], acc[i][j], 0, 0, 0);
    asm volatile("s_waitcnt lgkmcnt(0)" ::: "memory");  // all reads of bufc drained
    if (pf)                asm volatile("s_waitcnt vmcnt(4)" ::: "memory"); // t+1 landed
    else if (t + 1 < nt)   asm volatile("s_waitcnt vmcnt(0)" ::: "memory"); // tail drain
    __builtin_amdgcn_s_barrier();
    __builtin_amdgcn_sched_barrier(0);
    cur = cur == 2 ? 0 : cur + 1;
    nxt = nxt == 2 ? 0 : nxt + 1;
  }
#undef GLL

  // ---- output block -> (base, stride, byte offset, dtype), wave-uniform ----
  char* obase; int ostride, koff, isfp8;
  if (mode == 1) {
    int H = colBase >> 9, sel = (colBase >> 7) & 3;     // q,k,v,s; H = head
    if (sel == 0)      { obase = Cb;  ostride = 2304; koff = H * 256; isfp8 = 0; }
    else if (sel == 3) { obase = Cb2; ostride = 1024; koff = H * 256; isfp8 = 0; }
    else { obase = Cb; ostride = 2304;
           koff = 1024 + H * 256 + (sel == 2 ? 8 : 0); isfp8 = 1; }
  } else {
    obase = Cb; ostride = 2304;
    if (colBase == 768) { koff = 2048; isfp8 = 0; }
    else {
      int n2 = (colBase < 768) ? colBase : colBase - 896;
      int hb = (colBase < 768) ? 0 : 2;
      int hh = hb + n2 / 384, r = n2 % 384, sel = r >> 7;  // q,k,v
      if (sel == 0) { koff = hh * 256; isfp8 = 0; }
      else          { koff = 1024 + hh * 256 + (sel == 2 ? 8 : 0); isfp8 = 1; }
    }
  }

  // Epilogue: per-wave LDS repack in two 32-row halves (4 KB/wave region).
  // C/D layout col=lane&15, row=(lane>>4)*4+reg (m89-verified).
  ushort_t* wbuf = smem + wave * 2048;             // 32 x 64 bf16
  const int rq = lane >> 4, fc = lane & 15;
  float bv[4];
#pragma unroll
  for (int j = 0; j < 4; ++j) bv[j] = bias[colBase + wc * 64 + j * 16 + fc];
#pragma unroll
  for (int h = 0; h < 2; ++h) {
#pragma unroll
    for (int ii = 0; ii < 2; ++ii) {
      int i = h * 2 + ii;
#pragma unroll
      for (int j = 0; j < 4; ++j)
#pragma unroll
        for (int r = 0; r < 4; ++r) {
          int rl = ii * 16 + rq * 4 + r;          // 0..31 ; (rl>>2)&3 == rq
          int cl = j * 16 + fc;                   // 0..63
          int cs = cl ^ (rq << 4);                // rq -> bank octet
          wbuf[rl * 64 + cs] = f2bf(acc[i][j][r] + bv[j]);
        }
    }
    // read back: lanes 0..7 cover all 32 banks (ci*4); remap chunk by rq
    int ci = lane & 7;
    int rbase = lane >> 3;                         // 0..7
#pragma unroll
    for (int rg = 0; rg < 4; ++rg) {
      int rr = rg * 8 + rbase;                     // 0..31
      int rowg = rowBase + wr * 64 + h * 32 + rr;
      int cg = ci ^ (((rr >> 2) & 3) << 1);
      uint4 val = *(const uint4*)(wbuf + rr * 64 + (ci << 3));
      if (rowg < M) {
        char* dstRow = obase + (size_t)rowg * ostride + koff;
        if (!isfp8) {
          *(uint4*)(dstRow + (wc * 64 + cg * 8) * 2) = val;
        } else {
          float f[8];
          f[0] = bf2f((ushort_t)val.x); f[1] = bf2f((ushort_t)(val.x >> 16));
          f[2] = bf2f((ushort_t)val.y); f[3] = bf2f((ushort_t)(val.y >> 16));
          f[4] = bf2f((ushort_t)val.z); f[5] = bf2f((ushort_t)(val.z >> 16));
          f[6] = bf2f((ushort_t)val.w); f[7] = bf2f((ushort_t)(val.w >> 16));
          uint2 o;
          o.x = pack4_fp8(f[0], f[1], f[2], f[3]);
          o.y = pack4_fp8(f[4], f[5], f[6], f[7]);
          *(uint2*)(dstRow + ((wc * 8 + cg) << 4)) = o;   // kv interleave
        }
      }
    }
  }
}

// ---------------------------------------------------------------------------
// prep_all: one launch, four independent regions branch on blockIdx.x:
//  [0, NB_CVT)           : x fp32 -> bf16 (vectorized)
//  [NB_CVT, +NB_TP)      : weight 32x32 tile transposes -> W1t / W2t
//  [.., +NB_BIAS)        : bias permute -> Bh1 / Bh2
//  [.., +NB_ZERO)        : zero deg/counter/gstart/gend/pooled
// ---------------------------------------------------------------------------
#define L1_W   (2048 * FEAT)
#define L2_W   (1664 * HID)
#define T1     512   // (2048/32)*(256/32)
#define T2     832   // (1664/32)*(512/32)
#define NB_CVT  12500
#define NB_TP   (T1 + T2)
#define NB_BIAS 15
#define NB_ZERO 196

__global__ __launch_bounds__(256) void prep_all(
    const float* __restrict__ x, ushort_t* __restrict__ xb,
    const float* __restrict__ Wq1, const float* __restrict__ Wk1,
    const float* __restrict__ Wv1, const float* __restrict__ Ws1,
    const float* __restrict__ Wq2, const float* __restrict__ Wk2,
    const float* __restrict__ Wv2, const float* __restrict__ Ws2,
    const float* __restrict__ bq1, const float* __restrict__ bk1,
    const float* __restrict__ bv1, const float* __restrict__ bs1,
    const float* __restrict__ bq2, const float* __restrict__ bk2,
    const float* __restrict__ bv2, const float* __restrict__ bs2,
    ushort_t* __restrict__ W1t, ushort_t* __restrict__ W2t,
    float* __restrict__ Bh1, float* __restrict__ Bh2,
    int* __restrict__ deg, int* __restrict__ counter,
    int* __restrict__ gstart, int* __restrict__ gend,
    float* __restrict__ pooled) {
  __shared__ float tile[32][33];
  int blk = blockIdx.x;
  if (blk < NB_CVT) {
    int i = blk * 256 + threadIdx.x;            // n4 = 3.2M exactly
    float4 f = *(const float4*)(x + (size_t)i * 4);
    uint_t lo = (uint_t)f2bf(f.x) | ((uint_t)f2bf(f.y) << 16);
    uint_t hi = (uint_t)f2bf(f.z) | ((uint_t)f2bf(f.w) << 16);
    ((uint2*)xb)[i] = make_uint2(lo, hi);
    return;
  }
  blk -= NB_CVT;
  if (blk < NB_TP) {
    int t = blk;
    const float* W; int ldw, c0, n0, k0, ldk; ushort_t* dst;
    if (t < T1) {
      int nb = t >> 3, kb = t & 7;
      n0 = nb * 32; k0 = kb * 32; ldk = FEAT; dst = W1t;
      int p = n0 >> 10, n1 = n0 & 1023, hh = n1 >> 9, sel = (n1 >> 7) & 3;
      c0 = (2 * p + hh) * CH + (n1 & (CH - 1));
      W = sel == 0 ? Wq1 : sel == 1 ? Wk1 : sel == 2 ? Wv1 : Ws1;
      ldw = HID;
    } else {
      t -= T1;
      int nb = t >> 4, kb = t & 15;
      n0 = nb * 32; k0 = kb * 32; ldk = HID; dst = W2t;
      if (n0 < 768 || n0 >= 896) {
        int n2 = (n0 < 768) ? n0 : n0 - 896;
        int hb = (n0 < 768) ? 0 : 2;
        int hh = hb + n2 / 384, r = n2 % 384, sel = r >> 7;
        c0 = hh * CH + (r & (CH - 1));
        W = sel == 0 ? Wq2 : sel == 1 ? Wk2 : Wv2;
        ldw = HID;
      } else {
        c0 = n0 - 768; W = Ws2; ldw = CH;
      }
    }
    int col = threadIdx.x & 31, rw = threadIdx.x >> 5;
#pragma unroll
    for (int ph = 0; ph < 4; ++ph) {
      int kk = rw + ph * 8;
      tile[kk][col] = W[(size_t)(k0 + kk) * ldw + c0 + col];
    }
    __syncthreads();
#pragma unroll
    for (int ph = 0; ph < 4; ++ph) {
      int dn = rw + ph * 8;
      dst[(size_t)(n0 + dn) * ldk + k0 + col] = f2bf(tile[col][dn]);
    }
    return;
  }
  blk -= NB_TP;
  if (blk < NB_BIAS) {
    int n = blk * 256 + threadIdx.x;
    if (n < 2048) {
      int p = n >> 10, n1 = n & 1023, hh = n1 >> 9, sel = (n1 >> 7) & 3;
      int c = (2 * p + hh) * CH + (n1 & (CH - 1));
      const float* bb = sel == 0 ? bq1 : sel == 1 ? bk1 : sel == 2 ? bv1 : bs1;
      Bh1[n] = bb[c];
    } else if (n < 2048 + 1664) {
      int n2 = n - 2048;
      if (n2 < 768 || n2 >= 896) {
        int nn = (n2 < 768) ? n2 : n2 - 896;
        int hb = (n2 < 768) ? 0 : 2;
        int hh = hb + nn / 384, r = nn % 384, sel = r >> 7;
        int c = hh * CH + (r & (CH - 1));
        const float* bb = sel == 0 ? bq2 : sel == 1 ? bk2 : bv2;
        Bh2[n2] = bb[c];
      } else {
        Bh2[n2] = bs2[n2 - 768];
      }
    }
    return;
  }
  blk -= NB_BIAS;
  {
    int i = blk * 256 + threadIdx.x;
    if (i < N_NODES) deg[i] = 0;
    if (i < NGRAPH) { gstart[i] = 0; gend[i] = 0; }
    if (i < NGRAPH * CH) pooled[i] = 0.f;
    if (i == 0) counter[0] = 0;
  }
}

// ---------------------------------------------------------------------------
// CSR build: hist+bounds -> alloc (wave atomic) -> scatter
// ---------------------------------------------------------------------------
__global__ void hist_bounds_kernel(const int* __restrict__ dst, int* __restrict__ deg,
                                   const int* __restrict__ batch,
                                   int* __restrict__ gstart, int* __restrict__ gend) {
  int t = blockIdx.x * blockDim.x + threadIdx.x;
  if (t < EDGES) atomicAdd(&deg[dst[t]], 1);
  if (t < N_NODES) {
    int b = batch[t];
    if (t == 0 || batch[t - 1] != b) gstart[b] = t;
    if (t == N_NODES - 1 || batch[t + 1] != b) gend[b] = t + 1;
  }
}

__global__ void alloc_kernel(const int* __restrict__ deg, int* __restrict__ counter,
                             int* __restrict__ start, int* __restrict__ cursor) {
  int i = blockIdx.x * blockDim.x + threadIdx.x;
  int lane = threadIdx.x & 63;
  int v = (i < N_NODES) ? deg[i] : 0;
  int sum = v;
#pragma unroll
  for (int off = 1; off < 64; off <<= 1) {
    int t = __shfl_up(sum, off);
    if (lane >= off) sum += t;
  }
  int excl = sum - v;
  int waveTot = __shfl(sum, 63);
  int base = 0;
  if (lane == 63) base = atomicAdd(counter, waveTot);
  base = __shfl(base, 63);
  if (i < N_NODES) {
    start[i] = base + excl;
    cursor[i] = base + excl;
  }
}

__global__ void scatter_kernel(const int* __restrict__ src, const int* __restrict__ dst,
                               int* __restrict__ cursor, int* __restrict__ csr) {
  int e = blockIdx.x * blockDim.x + threadIdx.x;
  if (e < EDGES) {
    int pos = atomicAdd(&cursor[dst[e]], 1);
    csr[pos] = src[e];
  }
}

// ---------------------------------------------------------------------------
// Attention (round-14): HEAD-PER-GROUP + 4-WIDE edge pipeline. Degrees are
// Poisson(4), so 4-wide lets most nodes issue ALL their kv gathers in one
// batch (8 in flight with prefetch) instead of 2 dependent round-trips.
// Invalid slots masked by zeroing weights (cnt-guarded, wave-uniform).
// ---------------------------------------------------------------------------
#define INV_SQRT_CH 0.08838834764831845f

// layer 1: BIG row 2304 B: q_H @H*256, kv_H @1024+H*256. skip s_H in H1b
// @H*256 (written by L1 GEMM; loaded EARLY). Group g = head g; writes
// elu(msg_g + s_g) over H1b in place.
__global__ __launch_bounds__(256) void attn1_kernel(
    const char* __restrict__ BIG, const int* __restrict__ start,
    const int* __restrict__ deg, const int* __restrict__ csr,
    ushort_t* __restrict__ H1b) {
  int wave = threadIdx.x >> 6, lane = threadIdx.x & 63;
  int li = lane & 15, g = lane >> 4;               // g = head
  int i = blockIdx.x * 4 + wave;
  if (i >= N_NODES) return;
  int beg = start[i], end = beg + deg[i];
  const int kvoff = 1024 + g * 256 + li * 16;      // this lane's kv slot
  float q[8];
  unpack8(*(const uint4*)(BIG + (size_t)i * 2304 + g * 256 + li * 16), q);
  ushort_t* op8 = H1b + (size_t)i * HID + g * CH + li * 8;
  uint4 skw = *(const uint4*)op8;                  // early skip load
  float sA = 0.f, sB = 0.f, aA[8] = {}, aB[8] = {};
  if (beg < end) {
    const int last = end - 1;
#define KVLD(idx) (*(const uint4*)(BIG + \
    (size_t)csr[(idx) <= last ? (idx) : last] * 2304 + kvoff))
    uint4 kv0 = KVLD(beg),     kv1 = KVLD(beg + 1);
    uint4 kv2 = KVLD(beg + 2), kv3 = KVLD(beg + 3);
    for (int e = beg; e < end; e += 4) {
      int cnt = end - e;                           // wave-uniform
      uint4 kn0 = KVLD(e + 4), kn1 = KVLD(e + 5);
      uint4 kn2 = KVLD(e + 6), kn3 = KVLD(e + 7);
      float kf[8];
      unpack8_fp8(make_uint2(kv0.x, kv0.y), kf);
      float p0 = q[0]*kf[0]+q[1]*kf[1]+q[2]*kf[2]+q[3]*kf[3]+
                 q[4]*kf[4]+q[5]*kf[5]+q[6]*kf[6]+q[7]*kf[7];
      unpack8_fp8(make_uint2(kv1.x, kv1.y), kf);
      float p1 = q[0]*kf[0]+q[1]*kf[1]+q[2]*kf[2]+q[3]*kf[3]+
                 q[4]*kf[4]+q[5]*kf[5]+q[6]*kf[6]+q[7]*kf[7];
      unpack8_fp8(make_uint2(kv2.x, kv2.y), kf);
      float p2 = q[0]*kf[0]+q[1]*kf[1]+q[2]*kf[2]+q[3]*kf[3]+
                 q[4]*kf[4]+q[5]*kf[5]+q[6]*kf[6]+q[7]*kf[7];
      unpack8_fp8(make_uint2(kv3.x, kv3.y), kf);
      float p3 = q[0]*kf[0]+q[1]*kf[1]+q[2]*kf[2]+q[3]*kf[3]+
                 q[4]*kf[4]+q[5]*kf[5]+q[6]*kf[6]+q[7]*kf[7];
#pragma unroll
      for (int ox = 1; ox <= 8; ox <<= 1) {
        p0 += __shfl_xor(p0, ox); p1 += __shfl_xor(p1, ox);
        p2 += __shfl_xor(p2, ox); p3 += __shfl_xor(p3, ox);
      }
      float w0 = __expf(p0 * INV_SQRT_CH);
      float w1 = cnt > 1 ? __expf(p1 * INV_SQRT_CH) : 0.f;
      float w2 = cnt > 2 ? __expf(p2 * INV_SQRT_CH) : 0.f;
      float w3 = cnt > 3 ? __expf(p3 * INV_SQRT_CH) : 0.f;
      float vf[8];
      unpack8_fp8(make_uint2(kv0.z, kv0.w), vf);
      sA += w0;
#pragma unroll
      for (int c = 0; c < 8; ++c) aA[c] = fmaf(w0, vf[c], aA[c]);
      unpack8_fp8(make_uint2(kv1.z, kv1.w), vf);
      sB += w1;
#pragma unroll
      for (int c = 0; c < 8; ++c) aB[c] = fmaf(w1, vf[c], aB[c]);
      unpack8_fp8(make_uint2(kv2.z, kv2.w), vf);
      sA += w2;
#pragma unroll
      for (int c = 0; c < 8; ++c) aA[c] = fmaf(w2, vf[c], aA[c]);
      unpack8_fp8(make_uint2(kv3.z, kv3.w), vf);
      sB += w3;
#pragma unroll
      for (int c = 0; c < 8; ++c) aB[c] = fmaf(w3, vf[c], aB[c]);
      kv0 = kn0; kv1 = kn1; kv2 = kn2; kv3 = kn3;
    }
#undef KVLD
  }
  float inv = fastrcp(sA + sB + 1e-16f);
  float sk[8];
  unpack8(skw, sk);
  uint4 ow;
  uint_t* op = (uint_t*)&ow;
#pragma unroll
  for (int c = 0; c < 4; ++c) {
    float o0 = elu1((aA[2 * c] + aB[2 * c]) * inv + sk[2 * c]);
    float o1 = elu1((aA[2 * c + 1] + aB[2 * c + 1]) * inv + sk[2 * c + 1]);
    op[c] = (uint_t)f2bf(o0) | ((uint_t)f2bf(o1) << 16);
  }
  *(uint4*)op8 = ow;
}

// layer 2: row 2304 B: q_H @H*256, kv_H @1024+H*256, skip @2048.
// Group g = head g; 4-wide edge pipeline; per-group normalize (0.25/s_g),
// 8-value cross-group sum; group 0 writes POut[i][c]. pool adds skip.
__global__ __launch_bounds__(256) void attn2_kernel(
    const char* __restrict__ BIG, const int* __restrict__ start,
    const int* __restrict__ deg, const int* __restrict__ csr,
    ushort_t* __restrict__ POut) {
  int wave = threadIdx.x >> 6, lane = threadIdx.x & 63;
  int li = lane & 15, g = lane >> 4;               // g = head
  int i = blockIdx.x * 4 + wave;
  if (i >= N_NODES) return;
  int beg = start[i], end = beg + deg[i];
  const int kvoff = 1024 + g * 256 + li * 16;
  float q[8];
  unpack8(*(const uint4*)(BIG + (size_t)i * 2304 + g * 256 + li * 16), q);
  float sA = 0.f, sB = 0.f, aA[8] = {}, aB[8] = {};
  if (beg < end) {
    const int last = end - 1;
#define KVLD(idx) (*(const uint4*)(BIG + \
    (size_t)csr[(idx) <= last ? (idx) : last] * 2304 + kvoff))
    uint4 kv0 = KVLD(beg),     kv1 = KVLD(beg + 1);
    uint4 kv2 = KVLD(beg + 2), kv3 = KVLD(beg + 3);
    for (int e = beg; e < end; e += 4) {
      int cnt = end - e;                           // wave-uniform
      uint4 kn0 = KVLD(e + 4), kn1 = KVLD(e + 5);
      uint4 kn2 = KVLD(e + 6), kn3 = KVLD(e + 7);
      float kf[8];
      unpack8_fp8(make_uint2(kv0.x, kv0.y), kf);
      float p0 = q[0]*kf[0]+q[1]*kf[1]+q[2]*kf[2]+q[3]*kf[3]+
                 q[4]*kf[4]+q[5]*kf[5]+q[6]*kf[6]+q[7]*kf[7];
      unpack8_fp8(make_uint2(kv1.x, kv1.y), kf);
      float p1 = q[0]*kf[0]+q[1]*kf[1]+q[2]*kf[2]+q[3]*kf[3]+
                 q[4]*kf[4]+q[5]*kf[5]+q[6]*kf[6]+q[7]*kf[7];
      unpack8_fp8(make_uint2(kv2.x, kv2.y), kf);
      float p2 = q[0]*kf[0]+q[1]*kf[1]+q[2]*kf[2]+q[3]*kf[3]+
                 q[4]*kf[4]+q[5]*kf[5]+q[6]*kf[6]+q[7]*kf[7];
      unpack8_fp8(make_uint2(kv3.x, kv3.y), kf);
      float p3 = q[0]*kf[0]+q[1]*kf[1]+q[2]*kf[2]+q[3]*kf[3]+
                 q[4]*kf[4]+q[5]*kf[5]+q[6]*kf[6]+q[7]*kf[7];
#pragma unroll
      for (int ox = 1; ox <= 8; ox <<= 1) {
        p0 += __shfl_xor(p0, ox); p1 += __shfl_xor(p1, ox);
        p2 += __shfl_xor(p2, ox); p3 += __shfl_xor(p3, ox);
      }
      float w0 = __expf(p0 * INV_SQRT_CH);
      float w1 = cnt > 1 ? __expf(p1 * INV_SQRT_CH) : 0.f;
      float w2 = cnt > 2 ? __expf(p2 * INV_SQRT_CH) : 0.f;
      float w3 = cnt > 3 ? __expf(p3 * INV_SQRT_CH) : 0.f;
      float vf[8];
      unpack8_fp8(make_uint2(kv0.z, kv0.w), vf);
      sA += w0;
#pragma unroll
      for (int c = 0; c < 8; ++c) aA[c] = fmaf(w0, vf[c], aA[c]);
      unpack8_fp8(make_uint2(kv1.z, kv1.w), vf);
      sB += w1;
#pragma unroll
      for (int c = 0; c < 8; ++c) aB[c] = fmaf(w1, vf[c], aB[c]);
      unpack8_fp8(make_uint2(kv2.z, kv2.w), vf);
      sA += w2;
#pragma unroll
      for (int c = 0; c < 8; ++c) aA[c] = fmaf(w2, vf[c], aA[c]);
      unpack8_fp8(make_uint2(kv3.z, kv3.w), vf);
      sB += w3;
#pragma unroll
      for (int c = 0; c < 8; ++c) aB[c] = fmaf(w3, vf[c], aB[c]);
      kv0 = kn0; kv1 = kn1; kv2 = kn2; kv3 = kn3;
    }
#undef KVLD
  }
  float inv = 0.25f * fastrcp(sA + sB + 1e-16f);
  float o[8];
#pragma unroll
  for (int c = 0; c < 8; ++c) o[c] = (aA[c] + aB[c]) * inv;
#pragma unroll
  for (int ox = 16; ox <= 32; ox <<= 1)
#pragma unroll
    for (int c = 0; c < 8; ++c) o[c] += __shfl_xor(o[c], ox);
  if (g != 0) return;
  uint4 ow;
  uint_t* op = (uint_t*)&ow;
#pragma unroll
  for (int c = 0; c < 4; ++c)
    op[c] = (uint_t)f2bf(o[2 * c]) | ((uint_t)f2bf(o[2 * c + 1]) << 16);
  *(uint4*)(POut + (size_t)i * CH + li * 8) = ow;
}

// ---------------------------------------------------------------------------
// Pool (round-13 split, verified): pool_partial 256x8 blocks accumulating
// f32 partials into pooled[g][c] via atomics; cls_final does divide +
// logits + log_softmax per graph.
// ---------------------------------------------------------------------------
__global__ __launch_bounds__(256) void pool_partial(
    const ushort_t* __restrict__ POut, const char* __restrict__ BIG,
    const int* __restrict__ gstart, const int* __restrict__ gend,
    float* __restrict__ pooled) {
  int g = blockIdx.x, chunk = blockIdx.y;          // 8 chunks per graph
  int t = threadIdx.x;
  int c = t & (CH - 1), rr = t >> 7;
  int s0 = gstart[g], e0 = gend[g];
  float sum = 0.f;
  for (int i = s0 + chunk * 2 + rr; i < e0; i += 16) {
    float sk = bf2f(*(const ushort_t*)(BIG + (size_t)i * 2304 + 2048 + c * 2));
    float m0 = bf2f(POut[(size_t)i * CH + c]);
    sum += elu1(sk + m0);
  }
  atomicAdd(&pooled[g * CH + c], sum);
}

__global__ __launch_bounds__(256) void cls_final(
    const float* __restrict__ pooled, const int* __restrict__ gstart,
    const int* __restrict__ gend, const float* __restrict__ Wfc,
    const float* __restrict__ bfc, float* __restrict__ out) {
  int g = blockIdx.x * blockDim.x + threadIdx.x;   // one thread per graph
  if (g >= NGRAPH) return;
  float inv = 1.f / fmaxf((float)(gend[g] - gstart[g]), 1.f);
  float logits[NCLS];
#pragma unroll
  for (int cc = 0; cc < NCLS; ++cc) logits[cc] = bfc[cc];
  for (int c = 0; c < CH; ++c) {
    float p = pooled[g * CH + c] * inv;
#pragma unroll
    for (int cc = 0; cc < NCLS; ++cc)
      logits[cc] = fmaf(p, Wfc[c * NCLS + cc], logits[cc]);
  }
  float mx = -INFINITY;
#pragma unroll
  for (int cc = 0; cc < NCLS; ++cc) mx = fmaxf(mx, logits[cc]);
  float se = 0.f;
#pragma unroll
  for (int cc = 0; cc < NCLS; ++cc) se += expf(logits[cc] - mx);
  float ls = mx + logf(se);
#pragma unroll
  for (int cc = 0; cc < NCLS; ++cc) out[g * NCLS + cc] = logits[cc] - ls;
}

// ---------------------------------------------------------------------------
extern "C" void kernel_launch(void* const* d_in, const int* in_sizes, int n_in,
                              void* d_out, int out_size, void* d_ws, size_t ws_size,
                              hipStream_t stream) {
  const float* x    = (const float*)d_in[0];
  const int*   ei   = (const int*)d_in[1];
  const int*   batch= (const int*)d_in[2];
  const float* Wq1 = (const float*)d_in[3];  const float* bq1 = (const float*)d_in[4];
  const float* Wk1 = (const float*)d_in[5];  const float* bk1 = (const float*)d_in[6];
  const float* Wv1 = (const float*)d_in[7];  const float* bv1 = (const float*)d_in[8];
  const float* Ws1 = (const float*)d_in[9];  const float* bs1 = (const float*)d_in[10];
  const float* Wq2 = (const float*)d_in[11]; const float* bq2 = (const float*)d_in[12];
  const float* Wk2 = (const float*)d_in[13]; const float* bk2 = (const float*)d_in[14];
  const float* Wv2 = (const float*)d_in[15]; const float* bv2 = (const float*)d_in[16];
  const float* Ws2 = (const float*)d_in[17]; const float* bs2 = (const float*)d_in[18];
  const float* Wfc = (const float*)d_in[19]; const float* bfc = (const float*)d_in[20];
  float* out = (float*)d_out;

  // Workspace (~195 MB). POut (bf16 N*128 = 12.8MB) aliases xb (dead after
  // L1 GEMM). BIG rows are 2304 B for BOTH layers.
  ushort_t* xb     = (ushort_t*)d_ws;                   // N x 256 bf16 (25.6 MB)
  ushort_t* POut   = (ushort_t*)d_ws;                   // N x 128 bf16 (alias)
  char*     BIG    = (char*)(xb + (size_t)N_NODES * FEAT);  // N x 2304 B (115.2 MB)
  ushort_t* H1b    = (ushort_t*)(BIG + (size_t)N_NODES * 2304); // N x 512 bf16
  ushort_t* W1t    = H1b + (size_t)N_NODES * HID;       // 2048*256
  float*    Bh1    = (float*)(W1t + L1_W);              // 2048
  ushort_t* W2t    = (ushort_t*)(Bh1 + 2048);           // 1664*512
  float*    Bh2    = (float*)(W2t + L2_W);              // 1664
  int* deg    = (int*)(Bh2 + 1664);
  int* start  = deg + N_NODES;
  int* cursor = start + N_NODES;
  int* csr    = cursor + N_NODES;
  int* gstart = csr + EDGES;
  int* gend   = gstart + NGRAPH;
  int* counter= gend + NGRAPH;
  float* pooled = (float*)(counter + 1);                // 256*128 f32 (128 KB)

  const int* srcp = ei;
  const int* dstp = ei + EDGES;

  // ---- prep (single launch) + CSR build ----
  prep_all<<<NB_CVT + NB_TP + NB_BIAS + NB_ZERO, 256, 0, stream>>>(
      x, xb, Wq1, Wk1, Wv1, Ws1, Wq2, Wk2, Wv2, Ws2,
      bq1, bk1, bv1, bs1, bq2, bk2, bv2, bs2,
      W1t, W2t, Bh1, Bh2, deg, counter, gstart, gend, pooled);
  hist_bounds_kernel<<<(EDGES + 255) / 256, 256, 0, stream>>>(dstp, deg, batch, gstart, gend);
  alloc_kernel<<<(N_NODES + 255) / 256, 256, 0, stream>>>(deg, counter, start, cursor);
  scatter_kernel<<<(EDGES + 255) / 256, 256, 0, stream>>>(srcp, dstp, cursor, csr);

  const int ga = (N_NODES + 3) / 4;     // 12500

  // ---- layer 1: ONE GEMM (N=2048, 16 col tiles; q/kv -> BIG, s -> H1b),
  //      then ONE all-4-head attention (writes elu(msg+s) into H1b) ----
  gemm_bt<<<49 * 8 * 16, 256, 0, stream>>>(
      xb, W1t, Bh1, BIG, (char*)H1b, N_NODES, FEAT, 16, 1);
  attn1_kernel<<<ga, 256, 0, stream>>>(BIG, start, deg, csr, H1b);

  // ---- layer 2: ONE GEMM (13 col tiles, mode 2) + merged attention ----
  gemm_bt<<<49 * 8 * 13, 256, 0, stream>>>(
      H1b, W2t, Bh2, BIG, (char*)H1b, N_NODES, HID, 13, 2);
  attn2_kernel<<<ga, 256, 0, stream>>>(BIG, start, deg, csr, POut);

  // ---- pool (parallel partials + atomics) + classifier ----
  pool_partial<<<dim3(NGRAPH, 8), 256, 0, stream>>>(POut, BIG, gstart, gend, pooled);
  cls_final<<<1, 256, 0, stream>>>(pooled, gstart, gend, Wfc, bfc, out);
}